// Round 1
// baseline (65.424 us; speedup 1.0000x reference)
//
#include <hip/hip_runtime.h>
#include <hip/hip_bf16.h>
#include <math.h>

// ---------------------------------------------------------------------------
// Rejection sampler (speculative decoding) for MI355X.
//
// Dominant cost: argmax over target_logits [T, V=128000] fp32 (~295 MB read,
// memory-bound). Kernel 1 does one block per row, float4 loads, wave+LDS
// argmax reduce (first-occurrence tie-break like jnp.argmax). Kernel 2 does
// the trivial per-request accept/reject scan.
// ---------------------------------------------------------------------------

__device__ __forceinline__ void combine(float& bv, int& bi, float v, int i) {
    // prefer larger value; on tie prefer smaller index (jnp.argmax semantics)
    if (v > bv || (v == bv && i < bi)) { bv = v; bi = i; }
}

template <int BLOCK>
__global__ void __launch_bounds__(BLOCK)
argmax_rows_kernel(const float* __restrict__ logits, int vocab,
                   int* __restrict__ out_idx) {
    const int row = blockIdx.x;
    const float* rowp = logits + (size_t)row * (size_t)vocab;
    const int tid = threadIdx.x;

    float bv = -INFINITY;
    int   bi = 0x7fffffff;

    const int nv4 = vocab >> 2;                  // 128000/4 = 32000
    const float4* p4 = (const float4*)rowp;
    for (int j = tid; j < nv4; j += BLOCK) {
        float4 v = p4[j];
        const int base = j << 2;
        combine(bv, bi, v.x, base + 0);
        combine(bv, bi, v.y, base + 1);
        combine(bv, bi, v.z, base + 2);
        combine(bv, bi, v.w, base + 3);
    }
    // scalar tail (vocab % 4 != 0 safety; 128000 % 4 == 0 so normally empty)
    for (int j = (nv4 << 2) + tid; j < vocab; j += BLOCK) {
        combine(bv, bi, rowp[j], j);
    }

    // 64-lane wave butterfly-ish reduce (shfl_down)
    #pragma unroll
    for (int off = 32; off >= 1; off >>= 1) {
        float ov = __shfl_down(bv, off, 64);
        int   oi = __shfl_down(bi, off, 64);
        combine(bv, bi, ov, oi);
    }

    constexpr int NW = BLOCK / 64;
    __shared__ float sv[NW];
    __shared__ int   si[NW];
    const int wave = tid >> 6;
    if ((tid & 63) == 0) { sv[wave] = bv; si[wave] = bi; }
    __syncthreads();
    if (tid == 0) {
        #pragma unroll
        for (int w = 1; w < NW; ++w) combine(bv, bi, sv[w], si[w]);
        out_idx[row] = bi;
    }
}

__global__ void finalize_kernel(const int* __restrict__ draft,
                                const int* __restrict__ cu,
                                const int* __restrict__ argmax_idx,
                                const int* __restrict__ bonus,
                                int* __restrict__ out_tokens,   // [B, S+1]
                                int* __restrict__ out_bonus,    // [B]
                                int B, int S) {
    const int b = blockIdx.x * blockDim.x + threadIdx.x;
    if (b >= B) return;
    const int start = (b == 0) ? 0 : cu[b - 1];
    const int n     = cu[b] - start;             // in [1, S]
    int* row = out_tokens + (size_t)b * (S + 1);

    bool rejected  = false;
    int  processed = 0;
    for (int p = 0; p < S + 1; ++p) {
        int val;
        if (p < n) {
            if (!rejected) {
                const int t = argmax_idx[start + p];
                val = t;
                ++processed;
                if (draft[start + p] != t) rejected = true;  // argmax stored AT mismatch pos
            } else {
                val = -1;                                    // after first mismatch
            }
        } else if (p == n) {
            val = rejected ? -1 : bonus[b];                  // bonus slot
        } else {
            val = -1;                                        // past bonus
        }
        row[p] = val;
    }
    out_bonus[b] = processed - 1 + (rejected ? 0 : 1);
}

extern "C" void kernel_launch(void* const* d_in, const int* in_sizes, int n_in,
                              void* d_out, int out_size, void* d_ws, size_t ws_size,
                              hipStream_t stream) {
    // Inputs (setup_inputs order):
    //   0: draft_token_ids   int32 [T]
    //   1: num_spec_steps    int32 [1]   (derived host-side instead)
    //   2: cu_num_draft_tokens int32 [B]
    //   3: target_logits     float32 [T, V]
    //   4: bonus_token_ids   int32 [B]
    const int*   draft  = (const int*)d_in[0];
    const int*   cu     = (const int*)d_in[2];
    const float* logits = (const float*)d_in[3];
    const int*   bonus  = (const int*)d_in[4];

    const int T     = in_sizes[0];
    const int B     = in_sizes[2];
    const int vocab = in_sizes[3] / T;
    const int S     = out_size / B - 2;   // out = B*(S+1) + B

    int* argmax_buf = (int*)d_ws;         // T int32, fits easily in ws
    int* out_tokens = (int*)d_out;        // [B, S+1]
    int* out_bonus  = out_tokens + (size_t)B * (S + 1);

    constexpr int BLOCK = 512;            // 8 waves/block -> 4 blocks/CU
    argmax_rows_kernel<BLOCK><<<T, BLOCK, 0, stream>>>(logits, vocab, argmax_buf);
    finalize_kernel<<<(B + 127) / 128, 128, 0, stream>>>(
        draft, cu, argmax_buf, bonus, out_tokens, out_bonus, B, S);
}

// Round 2
// 59.206 us; speedup vs baseline: 1.1050x; 1.1050x over previous
//
#include <hip/hip_runtime.h>
#include <hip/hip_bf16.h>
#include <math.h>

// ---------------------------------------------------------------------------
// Rejection sampler (speculative decoding) for MI355X.
//
// Dominant cost: argmax over target_logits [T, V=128000] fp32 (~295 MB read,
// memory-bound). Phase 1: row-SEGMENTED argmax (NS=8 segments/row) for a
// balanced grid (~18 blocks/CU, tail imbalance <6% vs 33% with 1 block/row).
// Phase 2 (finalize): per-batch thread reduces its <=8 rows x 8 segment
// partials and runs the accept/reject scan.
// ---------------------------------------------------------------------------

typedef float f32x4 __attribute__((ext_vector_type(4)));

__device__ __forceinline__ void combine(float& bv, int& bi, float v, int i) {
    // prefer larger value; on tie prefer smaller index (jnp.argmax semantics)
    if (v > bv || (v == bv && i < bi)) { bv = v; bi = i; }
}

template <int BLOCK, int NS>
__global__ void __launch_bounds__(BLOCK)
argmax_partial_kernel(const float* __restrict__ logits, int vocab,
                      float* __restrict__ ws_val, int* __restrict__ ws_idx) {
    const int bid = blockIdx.x;
    const int row = bid / NS;
    const int seg = bid % NS;
    const int seg_len = vocab / NS;                 // 128000/8 = 16000 (mult of 4)
    const int seg_beg = seg * seg_len;
    const int seg_end = (seg == NS - 1) ? vocab : seg_beg + seg_len;

    const float* rowp = logits + (size_t)row * (size_t)vocab;
    const int tid = threadIdx.x;

    float bv = -INFINITY;
    int   bi = 0x7fffffff;

    const int beg4 = seg_beg >> 2;
    const int end4 = seg_end >> 2;                  // seg bounds are 4-aligned
    const f32x4* p4 = (const f32x4*)rowp;
    for (int j = beg4 + tid; j < end4; j += BLOCK) {
        f32x4 v = __builtin_nontemporal_load(&p4[j]);
        const int base = j << 2;
        combine(bv, bi, v.x, base + 0);
        combine(bv, bi, v.y, base + 1);
        combine(bv, bi, v.z, base + 2);
        combine(bv, bi, v.w, base + 3);
    }
    // scalar tail for non-multiple-of-4 vocab (normally empty)
    for (int j = (end4 << 2) + tid; j < seg_end; j += BLOCK) {
        combine(bv, bi, rowp[j], j);
    }

    // 64-lane wave reduce
    #pragma unroll
    for (int off = 32; off >= 1; off >>= 1) {
        float ov = __shfl_down(bv, off, 64);
        int   oi = __shfl_down(bi, off, 64);
        combine(bv, bi, ov, oi);
    }

    constexpr int NW = BLOCK / 64;
    __shared__ float sv[NW];
    __shared__ int   si[NW];
    const int wave = tid >> 6;
    if ((tid & 63) == 0) { sv[wave] = bv; si[wave] = bi; }
    __syncthreads();
    if (tid == 0) {
        #pragma unroll
        for (int w = 1; w < NW; ++w) combine(bv, bi, sv[w], si[w]);
        ws_val[bid] = bv;
        ws_idx[bid] = bi;
    }
}

template <int NS>
__global__ void finalize_kernel(const int* __restrict__ draft,
                                const int* __restrict__ cu,
                                const float* __restrict__ ws_val,
                                const int* __restrict__ ws_idx,
                                const int* __restrict__ bonus,
                                int* __restrict__ out_tokens,   // [B, S+1]
                                int* __restrict__ out_bonus,    // [B]
                                int B, int S) {
    const int b = blockIdx.x * blockDim.x + threadIdx.x;
    if (b >= B) return;
    const int start = (b == 0) ? 0 : cu[b - 1];
    const int n     = cu[b] - start;             // in [1, S]
    int* row = out_tokens + (size_t)b * (S + 1);

    bool rejected  = false;
    int  processed = 0;
    for (int p = 0; p < S + 1; ++p) {
        int val;
        if (p < n) {
            if (!rejected) {
                // reduce NS segment partials for draft position p
                const int base = (start + p) * NS;
                float bv = -INFINITY;
                int   bi = 0x7fffffff;
                #pragma unroll
                for (int s = 0; s < NS; ++s)
                    combine(bv, bi, ws_val[base + s], ws_idx[base + s]);
                val = bi;
                ++processed;
                if (draft[start + p] != bi) rejected = true; // argmax stored AT mismatch pos
            } else {
                val = -1;                                    // after first mismatch
            }
        } else if (p == n) {
            val = rejected ? -1 : bonus[b];                  // bonus slot
        } else {
            val = -1;                                        // past bonus
        }
        row[p] = val;
    }
    out_bonus[b] = processed - 1 + (rejected ? 0 : 1);
}

extern "C" void kernel_launch(void* const* d_in, const int* in_sizes, int n_in,
                              void* d_out, int out_size, void* d_ws, size_t ws_size,
                              hipStream_t stream) {
    // Inputs (setup_inputs order):
    //   0: draft_token_ids     int32 [T]
    //   1: num_spec_steps      int32 [1]   (derived host-side instead)
    //   2: cu_num_draft_tokens int32 [B]
    //   3: target_logits       float32 [T, V]
    //   4: bonus_token_ids     int32 [B]
    const int*   draft  = (const int*)d_in[0];
    const int*   cu     = (const int*)d_in[2];
    const float* logits = (const float*)d_in[3];
    const int*   bonus  = (const int*)d_in[4];

    const int T     = in_sizes[0];
    const int B     = in_sizes[2];
    const int vocab = in_sizes[3] / T;
    const int S     = out_size / B - 2;   // out = B*(S+1) + B

    constexpr int NS    = 8;              // segments per row
    constexpr int BLOCK = 256;            // 4 waves/block -> 8 blocks/CU resident

    float* ws_val = (float*)d_ws;                 // T*NS floats
    int*   ws_idx = (int*)(ws_val + (size_t)T * NS);
    int* out_tokens = (int*)d_out;                // [B, S+1]
    int* out_bonus  = out_tokens + (size_t)B * (S + 1);

    argmax_partial_kernel<BLOCK, NS><<<T * NS, BLOCK, 0, stream>>>(
        logits, vocab, ws_val, ws_idx);
    finalize_kernel<NS><<<(B + 127) / 128, 128, 0, stream>>>(
        draft, cu, ws_val, ws_idx, bonus, out_tokens, out_bonus, B, S);
}